// Round 3
// baseline (195.150 us; speedup 1.0000x reference)
//
#include <hip/hip_runtime.h>
#include <stdint.h>
#include <stddef.h>

#define B_ROWS 8192
#define NX 2048
#define NH 512
#define NY 1024

// prep kernel block split: elementwise cast blocks, then wq blocks
#define X_ELEMS (B_ROWS * NX)                 // 16777216 (relu+cast)
#define EW_ELEMS (X_ELEMS + NH * NX)          // + 1048576 (plain cast)
#define EW_BLOCKS (EW_ELEMS / (8 * 256))      // 8704
#define WQ_BLOCKS (NY / 4)                    // 256

typedef __attribute__((ext_vector_type(8))) short bf16x8;
typedef __attribute__((ext_vector_type(4))) float f32x4;

static __device__ __forceinline__ unsigned short f2bf(float f) {
    union { float f; unsigned int u; } c; c.f = f;
    unsigned int r = 0x7FFFu + ((c.u >> 16) & 1u);
    return (unsigned short)((c.u + r) >> 16);
}

static __device__ __forceinline__ void glld16(const void* g, void* l) {
    __builtin_amdgcn_global_load_lds(
        (const __attribute__((address_space(1))) unsigned int*)g,
        (__attribute__((address_space(3))) unsigned int*)l, 16, 0, 0);
}

// ---------------- prep: relu(x)->bf16, W_fc->bf16, W_q->bf16+rowsq ----------------
__global__ __launch_bounds__(256) void prep_kernel(const float* __restrict__ x,
                                                   const float* __restrict__ wfc,
                                                   const float* __restrict__ wq,
                                                   unsigned short* __restrict__ xb,
                                                   unsigned short* __restrict__ wfcb,
                                                   unsigned short* __restrict__ wqb,
                                                   float* __restrict__ wqsq) {
    const int bid = blockIdx.x;
    const int tid = threadIdx.x;
    if (bid < EW_BLOCKS) {
        size_t idx = ((size_t)bid * 256 + tid) * 8;
        if (idx < (size_t)X_ELEMS) {
            float4 a = *(const float4*)&x[idx];
            float4 b = *(const float4*)&x[idx + 4];
            bf16x8 o;
            o[0] = (short)f2bf(fmaxf(a.x, 0.f)); o[1] = (short)f2bf(fmaxf(a.y, 0.f));
            o[2] = (short)f2bf(fmaxf(a.z, 0.f)); o[3] = (short)f2bf(fmaxf(a.w, 0.f));
            o[4] = (short)f2bf(fmaxf(b.x, 0.f)); o[5] = (short)f2bf(fmaxf(b.y, 0.f));
            o[6] = (short)f2bf(fmaxf(b.z, 0.f)); o[7] = (short)f2bf(fmaxf(b.w, 0.f));
            *(bf16x8*)&xb[idx] = o;
        } else {
            size_t off = idx - X_ELEMS;
            float4 a = *(const float4*)&wfc[off];
            float4 b = *(const float4*)&wfc[off + 4];
            bf16x8 o;
            o[0] = (short)f2bf(a.x); o[1] = (short)f2bf(a.y);
            o[2] = (short)f2bf(a.z); o[3] = (short)f2bf(a.w);
            o[4] = (short)f2bf(b.x); o[5] = (short)f2bf(b.y);
            o[6] = (short)f2bf(b.z); o[7] = (short)f2bf(b.w);
            *(bf16x8*)&wfcb[off] = o;
        }
    } else {
        const int b2 = bid - EW_BLOCKS;        // 0..255
        const int lane = tid & 63;
        const int row = b2 * 4 + (tid >> 6);
        const float* p = wq + (size_t)row * NH + lane * 8;
        float4 a = *(const float4*)p;
        float4 b = *(const float4*)(p + 4);
        bf16x8 o;
        o[0] = (short)f2bf(a.x); o[1] = (short)f2bf(a.y);
        o[2] = (short)f2bf(a.z); o[3] = (short)f2bf(a.w);
        o[4] = (short)f2bf(b.x); o[5] = (short)f2bf(b.y);
        o[6] = (short)f2bf(b.z); o[7] = (short)f2bf(b.w);
        *(bf16x8*)&wqb[(size_t)row * NH + lane * 8] = o;
        float s = a.x*a.x + a.y*a.y + a.z*a.z + a.w*a.w
                + b.x*b.x + b.y*b.y + b.z*b.z + b.w*b.w;
        #pragma unroll
        for (int off = 32; off > 0; off >>= 1) s += __shfl_xor(s, off);
        if (lane == 0) wqsq[row] = s;
    }
}

// ---------------- fused: gemm1 + gemm2 + LSE, h never leaves LDS ----------------
// Block = 32 batch rows end-to-end. 1024 threads = 16 waves, 1 block/CU
// (LDS 160 KiB), 4 waves/SIMD. Grid = 256 = 1/CU.
//
// Phase 1: h[32][512] = relu(xb @ wfcb^T + b). Wave w owns h-cols [w*32,+32):
//   acc1 2x2. BK=32 dbuf (A 2x2 KiB, B1 2x32 KiB at P[0,68K)), 64 iters,
//   glld16 + gemm1's 64-B-row chunk swizzle (<=2-way b128 reads).
//   Epilogue: bias+relu -> h as bf16 into H[32][1024 B] with chunk-XOR swizzle
//   ch^(row&7) (phase-2 A reads are 16 rows x stride 1024 B -> needs it);
//   hsq reduced in-block (shfl over r + 32-thread LDS pass) -> regs. No HBM.
//
// Phase 2: R2's gemm2 inner loop; A-frags read from resident H, B2 = wqb
//   BK=32 dbuf (2x64 KiB = all of P). acc 2x4 over cols [w*64,+64).
//   Epilogue: d -> rcp/log (exp(t)=1/(1+d), NU=1), srow shfl + cross-wave LDS,
//   single out write. hb / hsq / lse kernels all gone.
__global__ __launch_bounds__(1024, 4) void fused_kernel(const unsigned short* __restrict__ xb,
                                                        const unsigned short* __restrict__ wfcb,
                                                        const unsigned short* __restrict__ wqb,
                                                        const float* __restrict__ b_fc,
                                                        const float* __restrict__ wqsq,
                                                        float* __restrict__ out) {
    __shared__ unsigned char smem[163840];
    char* P = (char*)smem;              // 128 KiB phase region
    char* H = (char*)smem + 131072;     // 32 KiB h tile: [32 rows][1024 B]

    const int tid = threadIdx.x;
    const int lane = tid & 63;
    const int wave = tid >> 6;          // 0..15
    const int quad = lane >> 4;
    const int r = lane & 15;
    const int m0 = blockIdx.x * 32;

    const int lrow = lane >> 2;                       // 0..15
    const int gch = (lane & 3) ^ ((lrow >> 1) & 3);   // swizzled 16B chunk (stage side)
    const int fsw = (quad ^ ((r >> 1) & 3)) * 16;     // fragment chunk byte offset

    // ---------------- phase 1 ----------------
    f32x4 acc1[2][2];
    #pragma unroll
    for (int i = 0; i < 2; ++i)
        #pragma unroll
        for (int j = 0; j < 2; ++j) acc1[i][j] = (f32x4)(0.0f);

    const char* asrc = (const char*)xb +
        (size_t)(m0 + (wave & 1) * 16 + lrow) * (NX * 2) + gch * 16;   // used by waves 0,1
    const char* b1src = (const char*)wfcb +
        (size_t)(wave * 32 + lrow) * (NX * 2) + gch * 16;

    auto stage1 = [&](int buf, int k0) {
        // B1: this wave's 32 wfcb rows (2 x 16-row groups)
        glld16(b1src + (size_t)k0 * 2, P + 4096 + buf * 32768 + (wave * 32) * 64);
        glld16(b1src + (size_t)(16 * NX + k0) * 2, P + 4096 + buf * 32768 + (wave * 32 + 16) * 64);
        // A: 32 xb rows, staged by waves 0 and 1
        if (wave < 2)
            glld16(asrc + (size_t)k0 * 2, P + buf * 2048 + wave * 1024);
    };

    stage1(0, 0);
    #pragma unroll 1
    for (int it = 0; it < NX / 32; ++it) {            // 64 iters
        __syncthreads();
        if (it + 1 < NX / 32) stage1((it + 1) & 1, it * 32 + 32);
        const char* ab = P + (it & 1) * 2048;
        const char* bb = P + 4096 + (it & 1) * 32768;
        bf16x8 af[2], bfv[2];
        #pragma unroll
        for (int i = 0; i < 2; ++i)
            af[i] = *(const bf16x8*)(ab + (i * 16 + r) * 64 + fsw);
        #pragma unroll
        for (int j = 0; j < 2; ++j)
            bfv[j] = *(const bf16x8*)(bb + (wave * 32 + j * 16 + r) * 64 + fsw);
        #pragma unroll
        for (int i = 0; i < 2; ++i)
            #pragma unroll
            for (int j = 0; j < 2; ++j)
                acc1[i][j] = __builtin_amdgcn_mfma_f32_16x16x32_bf16(af[i], bfv[j], acc1[i][j], 0, 0, 0);
    }

    // ---- epilogue 1: bias + relu -> H (bf16, ch^(row&7) swizzle), hsq in-block ----
    float psum[2][4];
    #pragma unroll
    for (int i = 0; i < 2; ++i)
        #pragma unroll
        for (int rr = 0; rr < 4; ++rr) psum[i][rr] = 0.0f;

    __syncthreads();                                  // (a) all P reads of phase 1 done
    #pragma unroll
    for (int j = 0; j < 2; ++j) {
        float bias = b_fc[wave * 32 + j * 16 + r];
        #pragma unroll
        for (int i = 0; i < 2; ++i) {
            #pragma unroll
            for (int rr = 0; rr < 4; ++rr) {
                float v = fmaxf(acc1[i][j][rr] + bias, 0.0f);
                int row = i * 16 + quad * 4 + rr;
                int col = wave * 32 + j * 16 + r;
                *(unsigned short*)(H + row * 1024 + (((col >> 3) ^ (row & 7)) * 16) + (col & 7) * 2) = f2bf(v);
                psum[i][rr] += v * v;
            }
        }
    }
    #pragma unroll
    for (int mask = 1; mask < 16; mask <<= 1)
        #pragma unroll
        for (int i = 0; i < 2; ++i)
            #pragma unroll
            for (int rr = 0; rr < 4; ++rr)
                psum[i][rr] += __shfl_xor(psum[i][rr], mask);

    float* scr = (float*)P;
    if (r == 0) {
        #pragma unroll
        for (int i = 0; i < 2; ++i)
            #pragma unroll
            for (int rr = 0; rr < 4; ++rr)
                scr[wave * 32 + i * 16 + quad * 4 + rr] = psum[i][rr];
    }
    __syncthreads();                                  // (b)
    if (tid < 32) {
        float s = 0.0f;
        #pragma unroll
        for (int w = 0; w < 16; ++w) s += scr[w * 32 + tid];
        scr[512 + tid] = s;
    }
    __syncthreads();                                  // (c)
    float hs_[2][4];
    #pragma unroll
    for (int i = 0; i < 2; ++i)
        #pragma unroll
        for (int rr = 0; rr < 4; ++rr)
            hs_[i][rr] = scr[512 + i * 16 + quad * 4 + rr];
    __syncthreads();                                  // (d) scr reads done before P reuse

    // ---------------- phase 2 ----------------
    f32x4 acc[2][4];
    #pragma unroll
    for (int i = 0; i < 2; ++i)
        #pragma unroll
        for (int j = 0; j < 4; ++j) acc[i][j] = (f32x4)(0.0f);

    const char* b2src = (const char*)wqb + (size_t)(wave * 64 + lrow) * (NH * 2) + gch * 16;
    auto stage2 = [&](int buf, int k0) {
        #pragma unroll
        for (int c = 0; c < 4; ++c)                   // this wave's 64 wqb rows
            glld16(b2src + (size_t)(c * 16 * NH + k0) * 2,
                   P + buf * 65536 + (wave * 64 + c * 16) * 64);
    };

    stage2(0, 0);
    #pragma unroll 1
    for (int it = 0; it < NH / 32; ++it) {            // 16 iters
        __syncthreads();
        if (it + 1 < NH / 32) stage2((it + 1) & 1, it * 32 + 32);
        const char* bb = P + (it & 1) * 65536;
        bf16x8 af[2], bfv[4];
        #pragma unroll
        for (int i = 0; i < 2; ++i)
            af[i] = *(const bf16x8*)(H + (i * 16 + r) * 1024 + (((it * 4 + quad) ^ (r & 7)) * 16));
        #pragma unroll
        for (int j = 0; j < 4; ++j)
            bfv[j] = *(const bf16x8*)(bb + (wave * 64 + j * 16 + r) * 64 + fsw);
        #pragma unroll
        for (int i = 0; i < 2; ++i)
            #pragma unroll
            for (int j = 0; j < 4; ++j)
                acc[i][j] = __builtin_amdgcn_mfma_f32_16x16x32_bf16(af[i], bfv[j], acc[i][j], 0, 0, 0);
    }

    // ---- epilogue 2: d, t, row-sums of exp(t) = 1/(1+d), LSE, store ----
    float srow[2][4];
    #pragma unroll
    for (int i = 0; i < 2; ++i)
        #pragma unroll
        for (int rr = 0; rr < 4; ++rr) srow[i][rr] = 0.0f;

    #pragma unroll
    for (int j = 0; j < 4; ++j) {
        float wqv = wqsq[wave * 64 + j * 16 + r];
        #pragma unroll
        for (int i = 0; i < 2; ++i) {
            #pragma unroll
            for (int rr = 0; rr < 4; ++rr) {
                float d = hs_[i][rr] - 2.0f * acc[i][j][rr] + wqv;
                d = fmaxf(d, 0.0f);
                float onepd = 1.0f + d;
                srow[i][rr] += __builtin_amdgcn_rcpf(onepd);
                acc[i][j][rr] = -__logf(onepd);       // keep t in-register
            }
        }
    }
    #pragma unroll
    for (int mask = 1; mask < 16; mask <<= 1)
        #pragma unroll
        for (int i = 0; i < 2; ++i)
            #pragma unroll
            for (int rr = 0; rr < 4; ++rr)
                srow[i][rr] += __shfl_xor(srow[i][rr], mask);

    float* smemF = (float*)P;
    __syncthreads();                                  // P reads of phase 2 done
    if (r == 0) {
        #pragma unroll
        for (int i = 0; i < 2; ++i)
            #pragma unroll
            for (int rr = 0; rr < 4; ++rr)
                smemF[wave * 32 + i * 16 + quad * 4 + rr] = srow[i][rr];
    }
    __syncthreads();
    if (tid < 32) {
        float S = 0.0f;
        #pragma unroll
        for (int w = 0; w < 16; ++w) S += smemF[w * 32 + tid];
        smemF[512 + tid] = __logf(S);
    }
    __syncthreads();

    #pragma unroll
    for (int i = 0; i < 2; ++i) {
        #pragma unroll
        for (int rr = 0; rr < 4; ++rr) {
            float l = smemF[512 + i * 16 + quad * 4 + rr];
            size_t rowoff = (size_t)(m0 + i * 16 + quad * 4 + rr) * NY + wave * 64 + r;
            #pragma unroll
            for (int j = 0; j < 4; ++j)
                out[rowoff + j * 16] = acc[i][j][rr] - l;
        }
    }
}

extern "C" void kernel_launch(void* const* d_in, const int* in_sizes, int n_in,
                              void* d_out, int out_size, void* d_ws, size_t ws_size,
                              hipStream_t stream) {
    const float* x    = (const float*)d_in[0];
    const float* W_fc = (const float*)d_in[1];
    const float* b_fc = (const float*)d_in[2];
    const float* W_q  = (const float*)d_in[3];
    float* out = (float*)d_out;

    char* ws = (char*)d_ws;
    unsigned short* xb   = (unsigned short*)(ws);                        // 32 MiB
    unsigned short* wfcb = (unsigned short*)(ws + 33554432);             // 2 MiB
    unsigned short* wqb  = (unsigned short*)(ws + 35651584);             // 1 MiB
    float*          wqsq = (float*)(ws + 36700160);                      // 4 KiB

    prep_kernel<<<EW_BLOCKS + WQ_BLOCKS, 256, 0, stream>>>(x, W_fc, W_q, xb, wfcb, wqb, wqsq);
    fused_kernel<<<B_ROWS / 32, 1024, 0, stream>>>(xb, wfcb, wqb, b_fc, wqsq, out);
}

// Round 4
// 177.692 us; speedup vs baseline: 1.0982x; 1.0982x over previous
//
#include <hip/hip_runtime.h>
#include <stdint.h>
#include <stddef.h>

#define B_ROWS 8192
#define NX 2048
#define NH 512
#define NY 1024

// prep kernel block split: elementwise cast blocks, then wq blocks
#define X_ELEMS (B_ROWS * NX)                 // 16777216 (relu+cast)
#define EW_ELEMS (X_ELEMS + NH * NX)          // + 1048576 (plain cast)
#define EW_BLOCKS (EW_ELEMS / (8 * 256))      // 8704
#define WQ_BLOCKS (NY / 4)                    // 256

typedef __attribute__((ext_vector_type(8))) short bf16x8;
typedef __attribute__((ext_vector_type(4))) float f32x4;

static __device__ __forceinline__ unsigned short f2bf(float f) {
    union { float f; unsigned int u; } c; c.f = f;
    unsigned int r = 0x7FFFu + ((c.u >> 16) & 1u);
    return (unsigned short)((c.u + r) >> 16);
}

static __device__ __forceinline__ void glld16(const void* g, void* l) {
    __builtin_amdgcn_global_load_lds(
        (const __attribute__((address_space(1))) unsigned int*)g,
        (__attribute__((address_space(3))) unsigned int*)l, 16, 0, 0);
}

// ---------------- prep: relu(x)->bf16, W_fc->bf16, W_q->bf16+rowsq, hsq=0 ----------------
__global__ __launch_bounds__(256) void prep_kernel(const float* __restrict__ x,
                                                   const float* __restrict__ wfc,
                                                   const float* __restrict__ wq,
                                                   unsigned short* __restrict__ xb,
                                                   unsigned short* __restrict__ wfcb,
                                                   unsigned short* __restrict__ wqb,
                                                   float* __restrict__ wqsq,
                                                   float* __restrict__ hsq) {
    const int bid = blockIdx.x;
    const int tid = threadIdx.x;
    if (bid < EW_BLOCKS) {
        size_t idx = ((size_t)bid * 256 + tid) * 8;
        if (idx < (size_t)X_ELEMS) {
            float4 a = *(const float4*)&x[idx];
            float4 b = *(const float4*)&x[idx + 4];
            bf16x8 o;
            o[0] = (short)f2bf(fmaxf(a.x, 0.f)); o[1] = (short)f2bf(fmaxf(a.y, 0.f));
            o[2] = (short)f2bf(fmaxf(a.z, 0.f)); o[3] = (short)f2bf(fmaxf(a.w, 0.f));
            o[4] = (short)f2bf(fmaxf(b.x, 0.f)); o[5] = (short)f2bf(fmaxf(b.y, 0.f));
            o[6] = (short)f2bf(fmaxf(b.z, 0.f)); o[7] = (short)f2bf(fmaxf(b.w, 0.f));
            *(bf16x8*)&xb[idx] = o;
        } else {
            size_t off = idx - X_ELEMS;
            float4 a = *(const float4*)&wfc[off];
            float4 b = *(const float4*)&wfc[off + 4];
            bf16x8 o;
            o[0] = (short)f2bf(a.x); o[1] = (short)f2bf(a.y);
            o[2] = (short)f2bf(a.z); o[3] = (short)f2bf(a.w);
            o[4] = (short)f2bf(b.x); o[5] = (short)f2bf(b.y);
            o[6] = (short)f2bf(b.z); o[7] = (short)f2bf(b.w);
            *(bf16x8*)&wfcb[off] = o;
        }
    } else {
        const int b2 = bid - EW_BLOCKS;        // 0..255
        const int lane = tid & 63;
        const int row = b2 * 4 + (tid >> 6);
        const float* p = wq + (size_t)row * NH + lane * 8;
        float4 a = *(const float4*)p;
        float4 b = *(const float4*)(p + 4);
        bf16x8 o;
        o[0] = (short)f2bf(a.x); o[1] = (short)f2bf(a.y);
        o[2] = (short)f2bf(a.z); o[3] = (short)f2bf(a.w);
        o[4] = (short)f2bf(b.x); o[5] = (short)f2bf(b.y);
        o[6] = (short)f2bf(b.z); o[7] = (short)f2bf(b.w);
        *(bf16x8*)&wqb[(size_t)row * NH + lane * 8] = o;
        float s = a.x*a.x + a.y*a.y + a.z*a.z + a.w*a.w
                + b.x*b.x + b.y*b.y + b.z*b.z + b.w*b.w;
        #pragma unroll
        for (int off = 32; off > 0; off >>= 1) s += __shfl_xor(s, off);
        if (lane == 0) wqsq[row] = s;
        if (tid < 32) hsq[b2 * 32 + tid] = 0.0f;   // zero-init for gemm1 atomics
    }
}

// ---------------- GEMM1: h = relu(xb @ wfcb^T + b) -> bf16 hb, fused hsq ----------------
// R3 post-mortem: grid must give >=2 blocks/CU so other blocks mask the
// vmcnt(0)+barrier drain. Tile M=128 x N=64 -> grid 64x8 = 512 = 2/CU.
// 512 threads = 8 waves (4 wm x 2 wn), wave-tile 32x32, acc 2x2, BK=32
// double-buffered LDS (A 2x8 KiB + B 2x4 KiB = 24 KiB), 64 iters.
// 64-B LDS rows; store-side chunk swizzle (gch) keeps b128 reads <=2-way.
__global__ __launch_bounds__(512, 4) void gemm1_kernel(const unsigned short* __restrict__ xb,
                                                       const unsigned short* __restrict__ wfcb,
                                                       const float* __restrict__ b_fc,
                                                       unsigned short* __restrict__ hb,
                                                       float* __restrict__ hsq) {
    __shared__ unsigned char smem[24576];
    unsigned char* AsB = smem;               // [buf][128 rows][64 B]
    unsigned char* BsB = smem + 16384;       // [buf][64 rows][64 B]

    const int tid = threadIdx.x;
    const int lane = tid & 63;
    const int wave = tid >> 6;               // 0..7
    const int wm = wave & 3;                 // row block 0..3 (32 rows each)
    const int wn = wave >> 2;                // col block 0..1 (32 cols each)
    const int quad = lane >> 4;
    const int r = lane & 15;

    // bid = c(3b XCD) | q(6b): n-tile = q&7, m-tile = c*8 + (q>>3)
    const int bid = blockIdx.x;              // 0..511
    const int c_ = bid & 7, q_ = bid >> 3;
    const int n0 = (q_ & 7) * 64;
    const int m0 = ((c_ << 3) | (q_ >> 3)) * 128;

    f32x4 acc[2][2];
    #pragma unroll
    for (int i = 0; i < 2; ++i)
        #pragma unroll
        for (int j = 0; j < 2; ++j) acc[i][j] = (f32x4)(0.0f);

    const int lrow = lane >> 2;                       // 0..15 (row within 16-row chunk)
    const int gch = (lane & 3) ^ ((lrow >> 1) & 3);   // swizzled 16B chunk
    const int fsw = (quad ^ ((r >> 1) & 3)) * 16;     // fragment chunk byte offset

    const char* asrc = (const char*)xb + (size_t)(m0 + wave * 16 + lrow) * (NX * 2) + gch * 16;
    const char* bsrc = (const char*)wfcb + (size_t)(n0 + (wave & 3) * 16 + lrow) * (NX * 2) + gch * 16;

    auto stage = [&](int buf, int k0) {
        glld16(asrc + (size_t)k0 * 2, AsB + buf * 8192 + wave * 1024);
        if (wave < 4)
            glld16(bsrc + (size_t)k0 * 2, BsB + buf * 4096 + wave * 1024);
    };

    stage(0, 0);
    #pragma unroll 1
    for (int it = 0; it < NX / 32; ++it) {            // 64 iters
        __syncthreads();
        if (it + 1 < NX / 32) stage((it + 1) & 1, it * 32 + 32);
        const unsigned char* ab = AsB + (it & 1) * 8192;
        const unsigned char* bb = BsB + (it & 1) * 4096;
        bf16x8 af[2], bfv[2];
        #pragma unroll
        for (int i = 0; i < 2; ++i)
            af[i] = *(const bf16x8*)(ab + (wm * 32 + i * 16 + r) * 64 + fsw);
        #pragma unroll
        for (int j = 0; j < 2; ++j)
            bfv[j] = *(const bf16x8*)(bb + (wn * 32 + j * 16 + r) * 64 + fsw);
        #pragma unroll
        for (int i = 0; i < 2; ++i)
            #pragma unroll
            for (int j = 0; j < 2; ++j)
                acc[i][j] = __builtin_amdgcn_mfma_f32_16x16x32_bf16(af[i], bfv[j], acc[i][j], 0, 0, 0);
    }

    // ---- epilogue: bias + relu -> hb, hsq partial (shuffle + atomic) ----
    float p[2][4];
    #pragma unroll
    for (int i = 0; i < 2; ++i)
        #pragma unroll
        for (int rr = 0; rr < 4; ++rr) p[i][rr] = 0.0f;

    #pragma unroll
    for (int j = 0; j < 2; ++j) {
        int col = n0 + wn * 32 + j * 16 + r;
        float bias = b_fc[col];
        #pragma unroll
        for (int i = 0; i < 2; ++i) {
            int rowb = m0 + wm * 32 + i * 16 + quad * 4;
            #pragma unroll
            for (int rr = 0; rr < 4; ++rr) {
                float v = fmaxf(acc[i][j][rr] + bias, 0.0f);
                hb[(size_t)(rowb + rr) * NH + col] = f2bf(v);
                p[i][rr] += v * v;
            }
        }
    }
    #pragma unroll
    for (int mask = 1; mask < 16; mask <<= 1)
        #pragma unroll
        for (int i = 0; i < 2; ++i)
            #pragma unroll
            for (int rr = 0; rr < 4; ++rr)
                p[i][rr] += __shfl_xor(p[i][rr], mask);
    if (r == 0) {
        #pragma unroll
        for (int i = 0; i < 2; ++i)
            #pragma unroll
            for (int rr = 0; rr < 4; ++rr)
                atomicAdd(&hsq[m0 + wm * 32 + i * 16 + quad * 4 + rr], p[i][rr]);
    }
}

// ---------------- GEMM2 fused with per-row LSE (single pass over out) ----------------
// NU=1  =>  t = -log1p(d)  =>  exp(t) = 1/(1+d): softmax denominator is a v_rcp
// on a register value -- no exp, no second out pass, no max (t <= 0).
// R3 post-mortem: must be 2 blocks/CU. M=32 x N=1024 (in-block LSE), 512 thr =
// 8 waves, wave-tile 32x128 (acc 2x8). BK=32 SINGLE-buffered B (64 KiB) +
// A (2 KiB) = 66 KiB -> 2 blocks/CU; the two resident blocks alternate
// stage/compute phases, replacing the double buffer. 16 iters, 2 barriers/iter.
__global__ __launch_bounds__(512, 4) void gemm2_kernel(const unsigned short* __restrict__ hb,
                                                       const unsigned short* __restrict__ wqb,
                                                       const float* __restrict__ hsq,
                                                       const float* __restrict__ wqsq,
                                                       float* __restrict__ out) {
    __shared__ unsigned char smem[67584];    // B 64 KiB + A 2 KiB (+ LSE scratch reuse)
    char* BsB = (char*)smem;                 // [1024 rows][64 B]
    char* AsB = (char*)smem + 65536;         // [32 rows][64 B]

    const int tid = threadIdx.x;
    const int lane = tid & 63;
    const int wave = tid >> 6;               // 0..7 -> col slab [wave*128, +128)
    const int quad = lane >> 4;
    const int r = lane & 15;
    const int m0 = blockIdx.x * 32;          // 256 blocks

    f32x4 acc[2][8];
    #pragma unroll
    for (int i = 0; i < 2; ++i)
        #pragma unroll
        for (int j = 0; j < 8; ++j) acc[i][j] = (f32x4)(0.0f);

    const int lrow = lane >> 2;                       // 0..15
    const int gch = (lane & 3) ^ ((lrow >> 1) & 3);   // swizzled 16B chunk
    const int fsw = (quad ^ ((r >> 1) & 3)) * 16;

    const char* bsrc = (const char*)wqb + (size_t)(wave * 128 + lrow) * (NH * 2) + gch * 16;
    const char* asrc = (const char*)hb + (size_t)(m0 + wave * 16 + lrow) * (NH * 2) + gch * 16;

    auto stage = [&](int k0) {
        #pragma unroll
        for (int c = 0; c < 8; ++c)                   // this wave's 128 B-rows
            glld16(bsrc + (size_t)(c * 16 * NH + k0) * 2,
                   BsB + (wave * 128 + c * 16) * 64);
        if (wave < 2)                                 // 32 A-rows
            glld16(asrc + (size_t)k0 * 2, AsB + wave * 1024);
    };

    #pragma unroll 1
    for (int it = 0; it < NH / 32; ++it) {            // 16 iters
        stage(it * 32);
        __syncthreads();                              // drain glld16 into LDS
        bf16x8 af[2];
        #pragma unroll
        for (int i = 0; i < 2; ++i)
            af[i] = *(const bf16x8*)(AsB + (i * 16 + r) * 64 + fsw);
        #pragma unroll
        for (int jh = 0; jh < 2; ++jh) {              // j-split keeps live VGPRs low
            bf16x8 bfv[4];
            #pragma unroll
            for (int j = 0; j < 4; ++j)
                bfv[j] = *(const bf16x8*)(BsB + (wave * 128 + jh * 64 + j * 16 + r) * 64 + fsw);
            #pragma unroll
            for (int i = 0; i < 2; ++i)
                #pragma unroll
                for (int j = 0; j < 4; ++j)
                    acc[i][jh * 4 + j] = __builtin_amdgcn_mfma_f32_16x16x32_bf16(af[i], bfv[j], acc[i][jh * 4 + j], 0, 0, 0);
        }
        __syncthreads();                              // reads done before next overwrite
    }

    // ---- epilogue: d, t, row-sums of exp(t) = 1/(1+d), LSE, store ----
    float hs_[2][4];
    #pragma unroll
    for (int i = 0; i < 2; ++i)
        #pragma unroll
        for (int rr = 0; rr < 4; ++rr)
            hs_[i][rr] = hsq[m0 + i * 16 + quad * 4 + rr];

    float srow[2][4];
    #pragma unroll
    for (int i = 0; i < 2; ++i)
        #pragma unroll
        for (int rr = 0; rr < 4; ++rr) srow[i][rr] = 0.0f;

    #pragma unroll
    for (int j = 0; j < 8; ++j) {
        float wqv = wqsq[wave * 128 + j * 16 + r];
        #pragma unroll
        for (int i = 0; i < 2; ++i) {
            #pragma unroll
            for (int rr = 0; rr < 4; ++rr) {
                float d = hs_[i][rr] - 2.0f * acc[i][j][rr] + wqv;
                d = fmaxf(d, 0.0f);
                float onepd = 1.0f + d;
                srow[i][rr] += __builtin_amdgcn_rcpf(onepd);
                acc[i][j][rr] = -__logf(onepd);       // keep t in-register
            }
        }
    }
    #pragma unroll
    for (int mask = 1; mask < 16; mask <<= 1)
        #pragma unroll
        for (int i = 0; i < 2; ++i)
            #pragma unroll
            for (int rr = 0; rr < 4; ++rr)
                srow[i][rr] += __shfl_xor(srow[i][rr], mask);

    float* smemF = (float*)smem;
    __syncthreads();                                  // LDS reads of K-loop done
    if (r == 0) {
        #pragma unroll
        for (int i = 0; i < 2; ++i)
            #pragma unroll
            for (int rr = 0; rr < 4; ++rr)
                smemF[wave * 32 + i * 16 + quad * 4 + rr] = srow[i][rr];
    }
    __syncthreads();
    if (tid < 32) {
        float S = 0.0f;
        #pragma unroll
        for (int w = 0; w < 8; ++w) S += smemF[w * 32 + tid];
        smemF[256 + tid] = __logf(S);
    }
    __syncthreads();

    #pragma unroll
    for (int i = 0; i < 2; ++i) {
        #pragma unroll
        for (int rr = 0; rr < 4; ++rr) {
            float l = smemF[256 + i * 16 + quad * 4 + rr];
            size_t rowoff = (size_t)(m0 + i * 16 + quad * 4 + rr) * NY + wave * 128 + r;
            #pragma unroll
            for (int j = 0; j < 8; ++j)
                out[rowoff + j * 16] = acc[i][j][rr] - l;
        }
    }
}

extern "C" void kernel_launch(void* const* d_in, const int* in_sizes, int n_in,
                              void* d_out, int out_size, void* d_ws, size_t ws_size,
                              hipStream_t stream) {
    const float* x    = (const float*)d_in[0];
    const float* W_fc = (const float*)d_in[1];
    const float* b_fc = (const float*)d_in[2];
    const float* W_q  = (const float*)d_in[3];
    float* out = (float*)d_out;

    char* ws = (char*)d_ws;
    unsigned short* xb   = (unsigned short*)(ws);                        // 32 MiB
    unsigned short* wfcb = (unsigned short*)(ws + 33554432);             // 2 MiB
    unsigned short* wqb  = (unsigned short*)(ws + 35651584);             // 1 MiB
    float*          wqsq = (float*)(ws + 36700160);                      // 4 KiB
    unsigned short* hb   = (unsigned short*)(ws + 36704256);             // 8 MiB
    float*          hsq  = (float*)(ws + 45092864);                      // 32 KiB

    prep_kernel<<<EW_BLOCKS + WQ_BLOCKS, 256, 0, stream>>>(x, W_fc, W_q, xb, wfcb, wqb, wqsq, hsq);
    gemm1_kernel<<<512, 512, 0, stream>>>(xb, wfcb, b_fc, hb, hsq);
    gemm2_kernel<<<B_ROWS / 32, 512, 0, stream>>>(hb, wqb, hsq, wqsq, out);
}

// Round 6
// 174.267 us; speedup vs baseline: 1.1198x; 1.0197x over previous
//
#include <hip/hip_runtime.h>
#include <stdint.h>
#include <stddef.h>

#define B_ROWS 8192
#define NX 2048
#define NH 512
#define NY 1024

// prep kernel block split: elementwise cast blocks, then wq blocks
#define X_ELEMS (B_ROWS * NX)                 // 16777216 (relu+cast)
#define EW_ELEMS (X_ELEMS + NH * NX)          // + 1048576 (plain cast)
#define EW_BLOCKS (EW_ELEMS / (8 * 256))      // 8704
#define WQ_BLOCKS (NY / 4)                    // 256

typedef __attribute__((ext_vector_type(8))) short bf16x8;
typedef __attribute__((ext_vector_type(4))) float f32x4;

static __device__ __forceinline__ unsigned short f2bf(float f) {
    union { float f; unsigned int u; } c; c.f = f;
    unsigned int r = 0x7FFFu + ((c.u >> 16) & 1u);
    return (unsigned short)((c.u + r) >> 16);
}

static __device__ __forceinline__ void glld16(const void* g, void* l) {
    __builtin_amdgcn_global_load_lds(
        (const __attribute__((address_space(1))) unsigned int*)g,
        (__attribute__((address_space(3))) unsigned int*)l, 16, 0, 0);
}

// ---------------- prep: relu(x)->bf16, W_fc->bf16, W_q->bf16+rowsq, hsq=0 ----------------
__global__ __launch_bounds__(256) void prep_kernel(const float* __restrict__ x,
                                                   const float* __restrict__ wfc,
                                                   const float* __restrict__ wq,
                                                   unsigned short* __restrict__ xb,
                                                   unsigned short* __restrict__ wfcb,
                                                   unsigned short* __restrict__ wqb,
                                                   float* __restrict__ wqsq,
                                                   float* __restrict__ hsq) {
    const int bid = blockIdx.x;
    const int tid = threadIdx.x;
    if (bid < EW_BLOCKS) {
        size_t idx = ((size_t)bid * 256 + tid) * 8;
        if (idx < (size_t)X_ELEMS) {
            float4 a = *(const float4*)&x[idx];
            float4 b = *(const float4*)&x[idx + 4];
            bf16x8 o;
            o[0] = (short)f2bf(fmaxf(a.x, 0.f)); o[1] = (short)f2bf(fmaxf(a.y, 0.f));
            o[2] = (short)f2bf(fmaxf(a.z, 0.f)); o[3] = (short)f2bf(fmaxf(a.w, 0.f));
            o[4] = (short)f2bf(fmaxf(b.x, 0.f)); o[5] = (short)f2bf(fmaxf(b.y, 0.f));
            o[6] = (short)f2bf(fmaxf(b.z, 0.f)); o[7] = (short)f2bf(fmaxf(b.w, 0.f));
            *(bf16x8*)&xb[idx] = o;
        } else {
            size_t off = idx - X_ELEMS;
            float4 a = *(const float4*)&wfc[off];
            float4 b = *(const float4*)&wfc[off + 4];
            bf16x8 o;
            o[0] = (short)f2bf(a.x); o[1] = (short)f2bf(a.y);
            o[2] = (short)f2bf(a.z); o[3] = (short)f2bf(a.w);
            o[4] = (short)f2bf(b.x); o[5] = (short)f2bf(b.y);
            o[6] = (short)f2bf(b.z); o[7] = (short)f2bf(b.w);
            *(bf16x8*)&wfcb[off] = o;
        }
    } else {
        const int b2 = bid - EW_BLOCKS;        // 0..255
        const int lane = tid & 63;
        const int row = b2 * 4 + (tid >> 6);
        const float* p = wq + (size_t)row * NH + lane * 8;
        float4 a = *(const float4*)p;
        float4 b = *(const float4*)(p + 4);
        bf16x8 o;
        o[0] = (short)f2bf(a.x); o[1] = (short)f2bf(a.y);
        o[2] = (short)f2bf(a.z); o[3] = (short)f2bf(a.w);
        o[4] = (short)f2bf(b.x); o[5] = (short)f2bf(b.y);
        o[6] = (short)f2bf(b.z); o[7] = (short)f2bf(b.w);
        *(bf16x8*)&wqb[(size_t)row * NH + lane * 8] = o;
        float s = a.x*a.x + a.y*a.y + a.z*a.z + a.w*a.w
                + b.x*b.x + b.y*b.y + b.z*b.z + b.w*b.w;
        #pragma unroll
        for (int off = 32; off > 0; off >>= 1) s += __shfl_xor(s, off);
        if (lane == 0) wqsq[row] = s;
        if (tid < 32) hsq[b2 * 32 + tid] = 0.0f;   // zero-init for gemm1 atomics
    }
}

// ---------------- GEMM1: h = relu(xb @ wfcb^T + b) -> bf16 hb, fused hsq ----------------
// Tile M=128 x N=64, grid 512 = 2 blocks/CU, 512 thr = 8 waves (4x2),
// wave-tile 32x32 (acc 2x2), BK=32 dbuf (24 KiB LDS).
// R4 post-mortem: __syncthreads() drains vmcnt(0) BEFORE compute -> zero overlap.
// R5: T3-minimum 2-phase schedule {stage(next); compute(cur); vmcnt(0); s_barrier}
// with raw asm + sched_barrier fences -- load latency hides under compute.
__global__ __launch_bounds__(512, 4) void gemm1_kernel(const unsigned short* __restrict__ xb,
                                                       const unsigned short* __restrict__ wfcb,
                                                       const float* __restrict__ b_fc,
                                                       unsigned short* __restrict__ hb,
                                                       float* __restrict__ hsq) {
    __shared__ unsigned char smem[24576];
    unsigned char* AsB = smem;               // [buf][128 rows][64 B]
    unsigned char* BsB = smem + 16384;       // [buf][64 rows][64 B]

    const int tid = threadIdx.x;
    const int lane = tid & 63;
    const int wave = tid >> 6;               // 0..7
    const int wm = wave & 3;                 // row block 0..3 (32 rows each)
    const int wn = wave >> 2;                // col block 0..1 (32 cols each)
    const int quad = lane >> 4;
    const int r = lane & 15;

    // bid = c(3b XCD) | q(6b): n-tile = q&7, m-tile = c*8 + (q>>3)
    const int bid = blockIdx.x;              // 0..511
    const int c_ = bid & 7, q_ = bid >> 3;
    const int n0 = (q_ & 7) * 64;
    const int m0 = ((c_ << 3) | (q_ >> 3)) * 128;

    f32x4 acc[2][2];
    #pragma unroll
    for (int i = 0; i < 2; ++i)
        #pragma unroll
        for (int j = 0; j < 2; ++j) acc[i][j] = (f32x4)(0.0f);

    const int lrow = lane >> 2;                       // 0..15 (row within 16-row chunk)
    const int gch = (lane & 3) ^ ((lrow >> 1) & 3);   // swizzled 16B chunk
    const int fsw = (quad ^ ((r >> 1) & 3)) * 16;     // fragment chunk byte offset

    const char* asrc = (const char*)xb + (size_t)(m0 + wave * 16 + lrow) * (NX * 2) + gch * 16;
    const char* bsrc = (const char*)wfcb + (size_t)(n0 + (wave & 3) * 16 + lrow) * (NX * 2) + gch * 16;

    auto stage = [&](int buf, int k0) {
        glld16(asrc + (size_t)k0 * 2, AsB + buf * 8192 + wave * 1024);
        if (wave < 4)
            glld16(bsrc + (size_t)k0 * 2, BsB + buf * 4096 + wave * 1024);
    };

    stage(0, 0);
    asm volatile("s_waitcnt vmcnt(0)" ::: "memory");
    __builtin_amdgcn_s_barrier();
    __builtin_amdgcn_sched_barrier(0);

    #pragma unroll 1
    for (int it = 0; it < NX / 32; ++it) {            // 64 iters
        if (it + 1 < NX / 32) stage((it + 1) & 1, it * 32 + 32);
        __builtin_amdgcn_sched_barrier(0);
        const unsigned char* ab = AsB + (it & 1) * 8192;
        const unsigned char* bb = BsB + (it & 1) * 4096;
        bf16x8 af[2], bfv[2];
        #pragma unroll
        for (int i = 0; i < 2; ++i)
            af[i] = *(const bf16x8*)(ab + (wm * 32 + i * 16 + r) * 64 + fsw);
        #pragma unroll
        for (int j = 0; j < 2; ++j)
            bfv[j] = *(const bf16x8*)(bb + (wn * 32 + j * 16 + r) * 64 + fsw);
        #pragma unroll
        for (int i = 0; i < 2; ++i)
            #pragma unroll
            for (int j = 0; j < 2; ++j)
                acc[i][j] = __builtin_amdgcn_mfma_f32_16x16x32_bf16(af[i], bfv[j], acc[i][j], 0, 0, 0);
        __builtin_amdgcn_sched_barrier(0);
        asm volatile("s_waitcnt vmcnt(0)" ::: "memory");
        __builtin_amdgcn_s_barrier();
        __builtin_amdgcn_sched_barrier(0);
    }

    // ---- epilogue: bias + relu -> hb, hsq partial (shuffle + atomic) ----
    float p[2][4];
    #pragma unroll
    for (int i = 0; i < 2; ++i)
        #pragma unroll
        for (int rr = 0; rr < 4; ++rr) p[i][rr] = 0.0f;

    #pragma unroll
    for (int j = 0; j < 2; ++j) {
        int col = n0 + wn * 32 + j * 16 + r;
        float bias = b_fc[col];
        #pragma unroll
        for (int i = 0; i < 2; ++i) {
            int rowb = m0 + wm * 32 + i * 16 + quad * 4;
            #pragma unroll
            for (int rr = 0; rr < 4; ++rr) {
                float v = fmaxf(acc[i][j][rr] + bias, 0.0f);
                hb[(size_t)(rowb + rr) * NH + col] = f2bf(v);
                p[i][rr] += v * v;
            }
        }
    }
    #pragma unroll
    for (int mask = 1; mask < 16; mask <<= 1)
        #pragma unroll
        for (int i = 0; i < 2; ++i)
            #pragma unroll
            for (int rr = 0; rr < 4; ++rr)
                p[i][rr] += __shfl_xor(p[i][rr], mask);
    if (r == 0) {
        #pragma unroll
        for (int i = 0; i < 2; ++i)
            #pragma unroll
            for (int rr = 0; rr < 4; ++rr)
                atomicAdd(&hsq[m0 + wm * 32 + i * 16 + quad * 4 + rr], p[i][rr]);
    }
}

// ---------------- GEMM2 fused with per-row LSE (single pass over out) ----------------
// NU=1  =>  t = -log1p(d)  =>  exp(t) = 1/(1+d): softmax denominator is a v_rcp.
// M=32 x N=1024 (in-block LSE), grid 256 = 1 block/CU. Intra-block overlap:
// A (32x512) staged ONCE into 32 KiB (16 slabs of [32][64 B]); B double-buffered
// 2x64 KiB; LDS = 160 KiB exactly. T3-minimum 2-phase loop: issue B(it+1),
// compute(it), vmcnt(0) asm, raw s_barrier -- one barrier/iter, drain AFTER
// compute so the 8 glld16/wave hide under 16 MFMAs + ds_reads.
__global__ __launch_bounds__(512, 2) void gemm2_kernel(const unsigned short* __restrict__ hb,
                                                       const unsigned short* __restrict__ wqb,
                                                       const float* __restrict__ hsq,
                                                       const float* __restrict__ wqsq,
                                                       float* __restrict__ out) {
    __shared__ unsigned char smem[163840];
    char* As = (char*)smem;                  // [16 slabs][32 rows][64 B] = 32 KiB (staged once)
    char* Bs = (char*)smem + 32768;          // [buf][1024 rows][64 B] = 2 x 64 KiB

    const int tid = threadIdx.x;
    const int lane = tid & 63;
    const int wave = tid >> 6;               // 0..7 -> col slab [wave*128, +128)
    const int quad = lane >> 4;
    const int r = lane & 15;
    const int m0 = blockIdx.x * 32;          // 256 blocks

    f32x4 acc[2][8];
    #pragma unroll
    for (int i = 0; i < 2; ++i)
        #pragma unroll
        for (int j = 0; j < 8; ++j) acc[i][j] = (f32x4)(0.0f);

    const int lrow = lane >> 2;                       // 0..15
    const int gch = (lane & 3) ^ ((lrow >> 1) & 3);   // swizzled 16B chunk
    const int fsw = (quad ^ ((r >> 1) & 3)) * 16;

    const char* bsrc = (const char*)wqb + (size_t)(wave * 128 + lrow) * (NH * 2) + gch * 16;

    auto stageB = [&](int buf, int k0) {
        #pragma unroll
        for (int c = 0; c < 8; ++c)                   // this wave's 128 B-rows
            glld16(bsrc + (size_t)(c * 16 * NH + k0) * 2,
                   Bs + buf * 65536 + (wave * 128 + c * 16) * 64);
    };

    // ---- prologue: stage all of A (wave w -> slabs 2w, 2w+1) + B slab 0 ----
    #pragma unroll
    for (int g = 0; g < 4; ++g) {
        int slab = 2 * wave + (g >> 1);
        int half = g & 1;
        glld16((const char*)hb + (size_t)(m0 + half * 16 + lrow) * (NH * 2) + slab * 64 + gch * 16,
               As + slab * 2048 + half * 1024);
    }
    stageB(0, 0);
    asm volatile("s_waitcnt vmcnt(0)" ::: "memory");
    __builtin_amdgcn_s_barrier();
    __builtin_amdgcn_sched_barrier(0);

    #pragma unroll 1
    for (int it = 0; it < NH / 32; ++it) {            // 16 iters
        if (it + 1 < NH / 32) stageB((it + 1) & 1, it * 32 + 32);
        __builtin_amdgcn_sched_barrier(0);
        const char* ab = As + it * 2048;
        const char* bb = Bs + (it & 1) * 65536;
        bf16x8 af[2];
        #pragma unroll
        for (int i = 0; i < 2; ++i)
            af[i] = *(const bf16x8*)(ab + (i * 16 + r) * 64 + fsw);
        #pragma unroll
        for (int jh = 0; jh < 2; ++jh) {              // j-split keeps live VGPRs low
            bf16x8 bfv[4];
            #pragma unroll
            for (int j = 0; j < 4; ++j)
                bfv[j] = *(const bf16x8*)(bb + (wave * 128 + jh * 64 + j * 16 + r) * 64 + fsw);
            #pragma unroll
            for (int i = 0; i < 2; ++i)
                #pragma unroll
                for (int j = 0; j < 4; ++j)
                    acc[i][jh * 4 + j] = __builtin_amdgcn_mfma_f32_16x16x32_bf16(af[i], bfv[j], acc[i][jh * 4 + j], 0, 0, 0);
        }
        __builtin_amdgcn_sched_barrier(0);
        asm volatile("s_waitcnt vmcnt(0)" ::: "memory");
        __builtin_amdgcn_s_barrier();
        __builtin_amdgcn_sched_barrier(0);
    }

    // ---- epilogue: d, t, row-sums of exp(t) = 1/(1+d), LSE, store ----
    float hs_[2][4];
    #pragma unroll
    for (int i = 0; i < 2; ++i)
        #pragma unroll
        for (int rr = 0; rr < 4; ++rr)
            hs_[i][rr] = hsq[m0 + i * 16 + quad * 4 + rr];

    float srow[2][4];
    #pragma unroll
    for (int i = 0; i < 2; ++i)
        #pragma unroll
        for (int rr = 0; rr < 4; ++rr) srow[i][rr] = 0.0f;

    #pragma unroll
    for (int j = 0; j < 8; ++j) {
        float wqv = wqsq[wave * 128 + j * 16 + r];
        #pragma unroll
        for (int i = 0; i < 2; ++i) {
            #pragma unroll
            for (int rr = 0; rr < 4; ++rr) {
                float d = hs_[i][rr] - 2.0f * acc[i][j][rr] + wqv;
                d = fmaxf(d, 0.0f);
                float onepd = 1.0f + d;
                srow[i][rr] += __builtin_amdgcn_rcpf(onepd);
                acc[i][j][rr] = -__logf(onepd);       // keep t in-register
            }
        }
    }
    #pragma unroll
    for (int mask = 1; mask < 16; mask <<= 1)
        #pragma unroll
        for (int i = 0; i < 2; ++i)
            #pragma unroll
            for (int rr = 0; rr < 4; ++rr)
                srow[i][rr] += __shfl_xor(srow[i][rr], mask);

    float* smemF = (float*)smem;                      // reuse As region (K-loop done)
    if (r == 0) {
        #pragma unroll
        for (int i = 0; i < 2; ++i)
            #pragma unroll
            for (int rr = 0; rr < 4; ++rr)
                smemF[wave * 32 + i * 16 + quad * 4 + rr] = srow[i][rr];
    }
    __syncthreads();
    if (tid < 32) {
        float S = 0.0f;
        #pragma unroll
        for (int w = 0; w < 8; ++w) S += smemF[w * 32 + tid];
        smemF[256 + tid] = __logf(S);
    }
    __syncthreads();

    #pragma unroll
    for (int i = 0; i < 2; ++i) {
        #pragma unroll
        for (int rr = 0; rr < 4; ++rr) {
            float l = smemF[256 + i * 16 + quad * 4 + rr];
            size_t rowoff = (size_t)(m0 + i * 16 + quad * 4 + rr) * NY + wave * 128 + r;
            #pragma unroll
            for (int j = 0; j < 8; ++j)
                out[rowoff + j * 16] = acc[i][j][rr] - l;
        }
    }
}

extern "C" void kernel_launch(void* const* d_in, const int* in_sizes, int n_in,
                              void* d_out, int out_size, void* d_ws, size_t ws_size,
                              hipStream_t stream) {
    const float* x    = (const float*)d_in[0];
    const float* W_fc = (const float*)d_in[1];
    const float* b_fc = (const float*)d_in[2];
    const float* W_q  = (const float*)d_in[3];
    float* out = (float*)d_out;

    char* ws = (char*)d_ws;
    unsigned short* xb   = (unsigned short*)(ws);                        // 32 MiB
    unsigned short* wfcb = (unsigned short*)(ws + 33554432);             // 2 MiB
    unsigned short* wqb  = (unsigned short*)(ws + 35651584);             // 1 MiB
    float*          wqsq = (float*)(ws + 36700160);                      // 4 KiB
    unsigned short* hb   = (unsigned short*)(ws + 36704256);             // 8 MiB
    float*          hsq  = (float*)(ws + 45092864);                      // 32 KiB

    prep_kernel<<<EW_BLOCKS + WQ_BLOCKS, 256, 0, stream>>>(x, W_fc, W_q, xb, wfcb, wqb, wqsq, hsq);
    gemm1_kernel<<<512, 512, 0, stream>>>(xb, wfcb, b_fc, hb, hsq);
    gemm2_kernel<<<B_ROWS / 32, 512, 0, stream>>>(hb, wqb, hsq, wqsq, out);
}

// Round 7
// 165.153 us; speedup vs baseline: 1.1816x; 1.0552x over previous
//
#include <hip/hip_runtime.h>
#include <stdint.h>
#include <stddef.h>

#define B_ROWS 8192
#define NX 2048
#define NH 512
#define NY 1024

// prep kernel block split: elementwise cast blocks, then wq blocks
#define X_ELEMS (B_ROWS * NX)                 // 16777216 (relu+cast)
#define EW_ELEMS (X_ELEMS + NH * NX)          // + 1048576 (plain cast)
#define EW_BLOCKS (EW_ELEMS / (8 * 256))      // 8704
#define WQ_BLOCKS (NY / 4)                    // 256

typedef __attribute__((ext_vector_type(8))) short bf16x8;
typedef __attribute__((ext_vector_type(4))) float f32x4;

static __device__ __forceinline__ unsigned short f2bf(float f) {
    union { float f; unsigned int u; } c; c.f = f;
    unsigned int r = 0x7FFFu + ((c.u >> 16) & 1u);
    return (unsigned short)((c.u + r) >> 16);
}

static __device__ __forceinline__ void glld16(const void* g, void* l) {
    __builtin_amdgcn_global_load_lds(
        (const __attribute__((address_space(1))) unsigned int*)g,
        (__attribute__((address_space(3))) unsigned int*)l, 16, 0, 0);
}

// ---------------- prep: relu(x)->bf16, W_fc->bf16, W_q->bf16+rowsq, hsq=0 ----------------
__global__ __launch_bounds__(256) void prep_kernel(const float* __restrict__ x,
                                                   const float* __restrict__ wfc,
                                                   const float* __restrict__ wq,
                                                   unsigned short* __restrict__ xb,
                                                   unsigned short* __restrict__ wfcb,
                                                   unsigned short* __restrict__ wqb,
                                                   float* __restrict__ wqsq,
                                                   float* __restrict__ hsq) {
    const int bid = blockIdx.x;
    const int tid = threadIdx.x;
    if (bid < EW_BLOCKS) {
        size_t idx = ((size_t)bid * 256 + tid) * 8;
        if (idx < (size_t)X_ELEMS) {
            float4 a = *(const float4*)&x[idx];
            float4 b = *(const float4*)&x[idx + 4];
            bf16x8 o;
            o[0] = (short)f2bf(fmaxf(a.x, 0.f)); o[1] = (short)f2bf(fmaxf(a.y, 0.f));
            o[2] = (short)f2bf(fmaxf(a.z, 0.f)); o[3] = (short)f2bf(fmaxf(a.w, 0.f));
            o[4] = (short)f2bf(fmaxf(b.x, 0.f)); o[5] = (short)f2bf(fmaxf(b.y, 0.f));
            o[6] = (short)f2bf(fmaxf(b.z, 0.f)); o[7] = (short)f2bf(fmaxf(b.w, 0.f));
            *(bf16x8*)&xb[idx] = o;
        } else {
            size_t off = idx - X_ELEMS;
            float4 a = *(const float4*)&wfc[off];
            float4 b = *(const float4*)&wfc[off + 4];
            bf16x8 o;
            o[0] = (short)f2bf(a.x); o[1] = (short)f2bf(a.y);
            o[2] = (short)f2bf(a.z); o[3] = (short)f2bf(a.w);
            o[4] = (short)f2bf(b.x); o[5] = (short)f2bf(b.y);
            o[6] = (short)f2bf(b.z); o[7] = (short)f2bf(b.w);
            *(bf16x8*)&wfcb[off] = o;
        }
    } else {
        const int b2 = bid - EW_BLOCKS;        // 0..255
        const int lane = tid & 63;
        const int row = b2 * 4 + (tid >> 6);
        const float* p = wq + (size_t)row * NH + lane * 8;
        float4 a = *(const float4*)p;
        float4 b = *(const float4*)(p + 4);
        bf16x8 o;
        o[0] = (short)f2bf(a.x); o[1] = (short)f2bf(a.y);
        o[2] = (short)f2bf(a.z); o[3] = (short)f2bf(a.w);
        o[4] = (short)f2bf(b.x); o[5] = (short)f2bf(b.y);
        o[6] = (short)f2bf(b.z); o[7] = (short)f2bf(b.w);
        *(bf16x8*)&wqb[(size_t)row * NH + lane * 8] = o;
        float s = a.x*a.x + a.y*a.y + a.z*a.z + a.w*a.w
                + b.x*b.x + b.y*b.y + b.z*b.z + b.w*b.w;
        #pragma unroll
        for (int off = 32; off > 0; off >>= 1) s += __shfl_xor(s, off);
        if (lane == 0) wqsq[row] = s;
        if (tid < 32) hsq[b2 * 32 + tid] = 0.0f;   // zero-init for gemm1 atomics
    }
}

// ---------------- GEMM1: h = relu(xb @ wfcb^T + b) -> bf16 hb, fused hsq ----------------
// Tile M=128 x N=64, grid 512 = 2 blocks/CU, 512 thr = 8 waves (4x2),
// wave-tile 32x32 (acc 2x2). R6 post-mortem: 1-deep vmcnt(0) drain = no window.
// R7: BK=64, THREE buffers, 2-deep prefetch, counted vmcnt(3) (uniform: every
// wave stages exactly 3 loads/iter: 2 A-groups + 1 B-group), one barrier/iter,
// vmcnt -> 0 only on the final iteration. Order per iter:
//   vmcnt(3) [my stage(it) landed] -> s_barrier [everyone's landed; compute(it-1)
//   reads done] -> stage(it+2) into buf (it+2)%3 [= buf read at it-1, now safe]
//   -> compute(it).
// 128-B LDS rows, chunk ^= (row&7) XOR swizzle (pre-swizzled global source,
// read chunk (s*4+quad)^(r&7)) keeps all b128 reads <=2-way (free).
__global__ __launch_bounds__(512, 4) void gemm1_kernel(const unsigned short* __restrict__ xb,
                                                       const unsigned short* __restrict__ wfcb,
                                                       const float* __restrict__ b_fc,
                                                       unsigned short* __restrict__ hb,
                                                       float* __restrict__ hsq) {
    __shared__ unsigned char smem[73728];
    unsigned char* AsB = smem;               // 3 bufs x [128 rows][128 B] = 48 KiB
    unsigned char* BsB = smem + 49152;       // 3 bufs x [64 rows][128 B]  = 24 KiB

    const int tid = threadIdx.x;
    const int lane = tid & 63;
    const int wave = tid >> 6;               // 0..7
    const int wm = wave & 3;                 // row block 0..3 (32 rows each)
    const int wn = wave >> 2;                // col block 0..1 (32 cols each)
    const int quad = lane >> 4;
    const int r = lane & 15;
    const int rx = r & 7;

    // bid = c(3b XCD) | q(6b): n-tile = q&7, m-tile = c*8 + (q>>3)
    const int bid = blockIdx.x;              // 0..511
    const int c_ = bid & 7, q_ = bid >> 3;
    const int n0 = (q_ & 7) * 64;
    const int m0 = ((c_ << 3) | (q_ >> 3)) * 128;

    f32x4 acc[2][2];
    #pragma unroll
    for (int i = 0; i < 2; ++i)
        #pragma unroll
        for (int j = 0; j < 2; ++j) acc[i][j] = (f32x4)(0.0f);

    const int lrow8 = lane >> 3;                      // 0..7 (row within 8-row group)
    const int gch8 = (lane & 7) ^ lrow8;              // pre-swizzled 16B source chunk

    const char* a0 = (const char*)xb + (size_t)(m0 + wave * 16 + lrow8) * (NX * 2) + gch8 * 16;
    const char* a1 = a0 + (size_t)8 * (NX * 2);
    const char* bsrc = (const char*)wfcb + (size_t)(n0 + wave * 8 + lrow8) * (NX * 2) + gch8 * 16;

    auto stage = [&](int bi, int k0) {                // 3 loads per wave, uniform
        glld16(a0 + (size_t)k0 * 2, AsB + bi * 16384 + (wave * 16) * 128);
        glld16(a1 + (size_t)k0 * 2, AsB + bi * 16384 + (wave * 16 + 8) * 128);
        glld16(bsrc + (size_t)k0 * 2, BsB + bi * 8192 + (wave * 8) * 128);
    };

    stage(0, 0);
    stage(1, 64);

    int cb = 0, sb = 2;
    #pragma unroll 1
    for (int it = 0; it < NX / 64; ++it) {            // 32 iters
        if (it == NX / 64 - 1) { asm volatile("s_waitcnt vmcnt(0)" ::: "memory"); }
        else                   { asm volatile("s_waitcnt vmcnt(3)" ::: "memory"); }
        __builtin_amdgcn_sched_barrier(0);
        __builtin_amdgcn_s_barrier();
        __builtin_amdgcn_sched_barrier(0);
        if (it + 2 < NX / 64) stage(sb, it * 64 + 128);
        __builtin_amdgcn_sched_barrier(0);
        const unsigned char* ab = AsB + cb * 16384;
        const unsigned char* bb = BsB + cb * 8192;
        #pragma unroll
        for (int s = 0; s < 2; ++s) {
            const int ch = ((s * 4 + quad) ^ rx) * 16;
            bf16x8 af[2], bfv[2];
            #pragma unroll
            for (int i = 0; i < 2; ++i)
                af[i] = *(const bf16x8*)(ab + (wm * 32 + i * 16 + r) * 128 + ch);
            #pragma unroll
            for (int j = 0; j < 2; ++j)
                bfv[j] = *(const bf16x8*)(bb + (wn * 32 + j * 16 + r) * 128 + ch);
            #pragma unroll
            for (int i = 0; i < 2; ++i)
                #pragma unroll
                for (int j = 0; j < 2; ++j)
                    acc[i][j] = __builtin_amdgcn_mfma_f32_16x16x32_bf16(af[i], bfv[j], acc[i][j], 0, 0, 0);
        }
        cb = (cb == 2) ? 0 : cb + 1;
        sb = (sb == 2) ? 0 : sb + 1;
    }

    // ---- epilogue: bias + relu -> hb, hsq partial (shuffle + atomic) ----
    float p[2][4];
    #pragma unroll
    for (int i = 0; i < 2; ++i)
        #pragma unroll
        for (int rr = 0; rr < 4; ++rr) p[i][rr] = 0.0f;

    #pragma unroll
    for (int j = 0; j < 2; ++j) {
        int col = n0 + wn * 32 + j * 16 + r;
        float bias = b_fc[col];
        #pragma unroll
        for (int i = 0; i < 2; ++i) {
            int rowb = m0 + wm * 32 + i * 16 + quad * 4;
            #pragma unroll
            for (int rr = 0; rr < 4; ++rr) {
                float v = fmaxf(acc[i][j][rr] + bias, 0.0f);
                hb[(size_t)(rowb + rr) * NH + col] = f2bf(v);
                p[i][rr] += v * v;
            }
        }
    }
    #pragma unroll
    for (int mask = 1; mask < 16; mask <<= 1)
        #pragma unroll
        for (int i = 0; i < 2; ++i)
            #pragma unroll
            for (int rr = 0; rr < 4; ++rr)
                p[i][rr] += __shfl_xor(p[i][rr], mask);
    if (r == 0) {
        #pragma unroll
        for (int i = 0; i < 2; ++i)
            #pragma unroll
            for (int rr = 0; rr < 4; ++rr)
                atomicAdd(&hsq[m0 + wm * 32 + i * 16 + quad * 4 + rr], p[i][rr]);
    }
}

// ---------------- GEMM2 fused with per-row LSE (single pass over out) ----------------
// NU=1  =>  t = -log1p(d)  =>  exp(t) = 1/(1+d): softmax denominator is a v_rcp.
// M=32 x N=1024 (in-block LSE), grid 256 = 1 block/CU.
// R7: B staging is WAVE-PRIVATE (wave w stages and reads only rows
// [w*128,+128)) and A is staged once in the prologue -- so after the one
// prologue barrier the K-loop needs NO barriers. Each wave free-runs:
//   {issue B(it+1) (8 glld16); s_waitcnt vmcnt(8) -> B(it) landed; compute(it)}
// vmcnt(0) only at the last iteration. TLP across 8 drifting waves hides the
// residual latency. __syncthreads() before the LDS scratch reuse in the epilogue.
__global__ __launch_bounds__(512, 2) void gemm2_kernel(const unsigned short* __restrict__ hb,
                                                       const unsigned short* __restrict__ wqb,
                                                       const float* __restrict__ hsq,
                                                       const float* __restrict__ wqsq,
                                                       float* __restrict__ out) {
    __shared__ unsigned char smem[163840];
    char* As = (char*)smem;                  // [16 slabs][32 rows][64 B] = 32 KiB (staged once)
    char* Bs = (char*)smem + 32768;          // [buf][1024 rows][64 B] = 2 x 64 KiB

    const int tid = threadIdx.x;
    const int lane = tid & 63;
    const int wave = tid >> 6;               // 0..7 -> col slab [wave*128, +128)
    const int quad = lane >> 4;
    const int r = lane & 15;
    const int m0 = blockIdx.x * 32;          // 256 blocks

    f32x4 acc[2][8];
    #pragma unroll
    for (int i = 0; i < 2; ++i)
        #pragma unroll
        for (int j = 0; j < 8; ++j) acc[i][j] = (f32x4)(0.0f);

    const int lrow = lane >> 2;                       // 0..15
    const int gch = (lane & 3) ^ ((lrow >> 1) & 3);   // swizzled 16B chunk
    const int fsw = (quad ^ ((r >> 1) & 3)) * 16;

    const char* bsrc = (const char*)wqb + (size_t)(wave * 128 + lrow) * (NH * 2) + gch * 16;

    auto stageB = [&](int buf, int k0) {
        #pragma unroll
        for (int c = 0; c < 8; ++c)                   // this wave's 128 B-rows
            glld16(bsrc + (size_t)(c * 16 * NH + k0) * 2,
                   Bs + buf * 65536 + (wave * 128 + c * 16) * 64);
    };

    // ---- prologue: stage all of A (wave w -> slabs 2w, 2w+1) + B slab 0 ----
    #pragma unroll
    for (int g = 0; g < 4; ++g) {
        int slab = 2 * wave + (g >> 1);
        int half = g & 1;
        glld16((const char*)hb + (size_t)(m0 + half * 16 + lrow) * (NH * 2) + slab * 64 + gch * 16,
               As + slab * 2048 + half * 1024);
    }
    stageB(0, 0);
    asm volatile("s_waitcnt vmcnt(8)" ::: "memory");  // A landed; B(0) may fly
    __builtin_amdgcn_sched_barrier(0);
    __builtin_amdgcn_s_barrier();
    __builtin_amdgcn_sched_barrier(0);

    #pragma unroll 1
    for (int it = 0; it < NH / 32; ++it) {            // 16 iters, NO barriers
        if (it + 1 < NH / 32) stageB((it + 1) & 1, it * 32 + 32);
        __builtin_amdgcn_sched_barrier(0);
        if (it == NH / 32 - 1) { asm volatile("s_waitcnt vmcnt(0)" ::: "memory"); }
        else                   { asm volatile("s_waitcnt vmcnt(8)" ::: "memory"); }
        __builtin_amdgcn_sched_barrier(0);
        const char* ab = As + it * 2048;
        const char* bb = Bs + (it & 1) * 65536;
        bf16x8 af[2];
        #pragma unroll
        for (int i = 0; i < 2; ++i)
            af[i] = *(const bf16x8*)(ab + (i * 16 + r) * 64 + fsw);
        #pragma unroll
        for (int jh = 0; jh < 2; ++jh) {              // j-split keeps live VGPRs low
            bf16x8 bfv[4];
            #pragma unroll
            for (int j = 0; j < 4; ++j)
                bfv[j] = *(const bf16x8*)(bb + (wave * 128 + jh * 64 + j * 16 + r) * 64 + fsw);
            #pragma unroll
            for (int i = 0; i < 2; ++i)
                #pragma unroll
                for (int j = 0; j < 4; ++j)
                    acc[i][jh * 4 + j] = __builtin_amdgcn_mfma_f32_16x16x32_bf16(af[i], bfv[j], acc[i][jh * 4 + j], 0, 0, 0);
        }
    }

    // ---- epilogue: d, t, row-sums of exp(t) = 1/(1+d), LSE, store ----
    float hs_[2][4];
    #pragma unroll
    for (int i = 0; i < 2; ++i)
        #pragma unroll
        for (int rr = 0; rr < 4; ++rr)
            hs_[i][rr] = hsq[m0 + i * 16 + quad * 4 + rr];

    float srow[2][4];
    #pragma unroll
    for (int i = 0; i < 2; ++i)
        #pragma unroll
        for (int rr = 0; rr < 4; ++rr) srow[i][rr] = 0.0f;

    #pragma unroll
    for (int j = 0; j < 8; ++j) {
        float wqv = wqsq[wave * 128 + j * 16 + r];
        #pragma unroll
        for (int i = 0; i < 2; ++i) {
            #pragma unroll
            for (int rr = 0; rr < 4; ++rr) {
                float d = hs_[i][rr] - 2.0f * acc[i][j][rr] + wqv;
                d = fmaxf(d, 0.0f);
                float onepd = 1.0f + d;
                srow[i][rr] += __builtin_amdgcn_rcpf(onepd);
                acc[i][j][rr] = -__logf(onepd);       // keep t in-register
            }
        }
    }
    #pragma unroll
    for (int mask = 1; mask < 16; mask <<= 1)
        #pragma unroll
        for (int i = 0; i < 2; ++i)
            #pragma unroll
            for (int rr = 0; rr < 4; ++rr)
                srow[i][rr] += __shfl_xor(srow[i][rr], mask);

    float* smemF = (float*)smem;                      // reuse As region
    __syncthreads();                                  // ALL waves out of K-loop first
    if (r == 0) {
        #pragma unroll
        for (int i = 0; i < 2; ++i)
            #pragma unroll
            for (int rr = 0; rr < 4; ++rr)
                smemF[wave * 32 + i * 16 + quad * 4 + rr] = srow[i][rr];
    }
    __syncthreads();
    if (tid < 32) {
        float S = 0.0f;
        #pragma unroll
        for (int w = 0; w < 8; ++w) S += smemF[w * 32 + tid];
        smemF[256 + tid] = __logf(S);
    }
    __syncthreads();

    #pragma unroll
    for (int i = 0; i < 2; ++i) {
        #pragma unroll
        for (int rr = 0; rr < 4; ++rr) {
            float l = smemF[256 + i * 16 + quad * 4 + rr];
            size_t rowoff = (size_t)(m0 + i * 16 + quad * 4 + rr) * NY + wave * 128 + r;
            #pragma unroll
            for (int j = 0; j < 8; ++j)
                out[rowoff + j * 16] = acc[i][j][rr] - l;
        }
    }
}

extern "C" void kernel_launch(void* const* d_in, const int* in_sizes, int n_in,
                              void* d_out, int out_size, void* d_ws, size_t ws_size,
                              hipStream_t stream) {
    const float* x    = (const float*)d_in[0];
    const float* W_fc = (const float*)d_in[1];
    const float* b_fc = (const float*)d_in[2];
    const float* W_q  = (const float*)d_in[3];
    float* out = (float*)d_out;

    char* ws = (char*)d_ws;
    unsigned short* xb   = (unsigned short*)(ws);                        // 32 MiB
    unsigned short* wfcb = (unsigned short*)(ws + 33554432);             // 2 MiB
    unsigned short* wqb  = (unsigned short*)(ws + 35651584);             // 1 MiB
    float*          wqsq = (float*)(ws + 36700160);                      // 4 KiB
    unsigned short* hb   = (unsigned short*)(ws + 36704256);             // 8 MiB
    float*          hsq  = (float*)(ws + 45092864);                      // 32 KiB

    prep_kernel<<<EW_BLOCKS + WQ_BLOCKS, 256, 0, stream>>>(x, W_fc, W_q, xb, wfcb, wqb, wqsq, hsq);
    gemm1_kernel<<<512, 512, 0, stream>>>(xb, wfcb, b_fc, hb, hsq);
    gemm2_kernel<<<B_ROWS / 32, 512, 0, stream>>>(hb, wqb, hsq, wqsq, out);
}

// Round 8
// 159.815 us; speedup vs baseline: 1.2211x; 1.0334x over previous
//
#include <hip/hip_runtime.h>
#include <stdint.h>
#include <stddef.h>

#define B_ROWS 8192
#define NX 2048
#define NH 512
#define NY 1024

// prep kernel block split: elementwise cast blocks, then wq blocks
#define X_ELEMS (B_ROWS * NX)                 // 16777216 (relu+cast)
#define EW_ELEMS (X_ELEMS + NH * NX)          // + 1048576 (plain cast)
#define EW_BLOCKS (EW_ELEMS / (8 * 256))      // 8704
#define WQ_BLOCKS (NY / 4)                    // 256

typedef __attribute__((ext_vector_type(8))) short bf16x8;
typedef __attribute__((ext_vector_type(4))) float f32x4;

static __device__ __forceinline__ unsigned short f2bf(float f) {
    union { float f; unsigned int u; } c; c.f = f;
    unsigned int r = 0x7FFFu + ((c.u >> 16) & 1u);
    return (unsigned short)((c.u + r) >> 16);
}

static __device__ __forceinline__ void glld16(const void* g, void* l) {
    __builtin_amdgcn_global_load_lds(
        (const __attribute__((address_space(1))) unsigned int*)g,
        (__attribute__((address_space(3))) unsigned int*)l, 16, 0, 0);
}

// ---------------- prep: relu(x)->bf16, W_fc->bf16, W_q->bf16+rowsq, hsq=0 ----------------
__global__ __launch_bounds__(256) void prep_kernel(const float* __restrict__ x,
                                                   const float* __restrict__ wfc,
                                                   const float* __restrict__ wq,
                                                   unsigned short* __restrict__ xb,
                                                   unsigned short* __restrict__ wfcb,
                                                   unsigned short* __restrict__ wqb,
                                                   float* __restrict__ wqsq,
                                                   float* __restrict__ hsq) {
    const int bid = blockIdx.x;
    const int tid = threadIdx.x;
    if (bid < EW_BLOCKS) {
        size_t idx = ((size_t)bid * 256 + tid) * 8;
        if (idx < (size_t)X_ELEMS) {
            float4 a = *(const float4*)&x[idx];
            float4 b = *(const float4*)&x[idx + 4];
            bf16x8 o;
            o[0] = (short)f2bf(fmaxf(a.x, 0.f)); o[1] = (short)f2bf(fmaxf(a.y, 0.f));
            o[2] = (short)f2bf(fmaxf(a.z, 0.f)); o[3] = (short)f2bf(fmaxf(a.w, 0.f));
            o[4] = (short)f2bf(fmaxf(b.x, 0.f)); o[5] = (short)f2bf(fmaxf(b.y, 0.f));
            o[6] = (short)f2bf(fmaxf(b.z, 0.f)); o[7] = (short)f2bf(fmaxf(b.w, 0.f));
            *(bf16x8*)&xb[idx] = o;
        } else {
            size_t off = idx - X_ELEMS;
            float4 a = *(const float4*)&wfc[off];
            float4 b = *(const float4*)&wfc[off + 4];
            bf16x8 o;
            o[0] = (short)f2bf(a.x); o[1] = (short)f2bf(a.y);
            o[2] = (short)f2bf(a.z); o[3] = (short)f2bf(a.w);
            o[4] = (short)f2bf(b.x); o[5] = (short)f2bf(b.y);
            o[6] = (short)f2bf(b.z); o[7] = (short)f2bf(b.w);
            *(bf16x8*)&wfcb[off] = o;
        }
    } else {
        const int b2 = bid - EW_BLOCKS;        // 0..255
        const int lane = tid & 63;
        const int row = b2 * 4 + (tid >> 6);
        const float* p = wq + (size_t)row * NH + lane * 8;
        float4 a = *(const float4*)p;
        float4 b = *(const float4*)(p + 4);
        bf16x8 o;
        o[0] = (short)f2bf(a.x); o[1] = (short)f2bf(a.y);
        o[2] = (short)f2bf(a.z); o[3] = (short)f2bf(a.w);
        o[4] = (short)f2bf(b.x); o[5] = (short)f2bf(b.y);
        o[6] = (short)f2bf(b.z); o[7] = (short)f2bf(b.w);
        *(bf16x8*)&wqb[(size_t)row * NH + lane * 8] = o;
        float s = a.x*a.x + a.y*a.y + a.z*a.z + a.w*a.w
                + b.x*b.x + b.y*b.y + b.z*b.z + b.w*b.w;
        #pragma unroll
        for (int off = 32; off > 0; off >>= 1) s += __shfl_xor(s, off);
        if (lane == 0) wqsq[row] = s;
        if (tid < 32) hsq[b2 * 32 + tid] = 0.0f;   // zero-init for gemm1 atomics
    }
}

// ---------------- GEMM1: h = relu(xb @ wfcb^T + b) -> bf16 hb, fused hsq ----------------
// Tile M=128 x N=64, grid 512 = 2 blocks/CU, 512 thr = 8 waves (4x2),
// wave-tile 32x32 (acc 2x2). BK=64, THREE buffers, 2-deep prefetch, counted
// vmcnt(3) (uniform 3 loads/wave/iter), one barrier/iter, vmcnt->0 only at the
// final iteration. Order per iter: vmcnt(3) [stage(it) landed] -> s_barrier ->
// stage(it+2) into buf (it+2)%3 [read at it-1, safe] -> compute(it).
// 128-B LDS rows, chunk ^= (row&7) XOR swizzle keeps b128 reads <=2-way.
__global__ __launch_bounds__(512, 4) void gemm1_kernel(const unsigned short* __restrict__ xb,
                                                       const unsigned short* __restrict__ wfcb,
                                                       const float* __restrict__ b_fc,
                                                       unsigned short* __restrict__ hb,
                                                       float* __restrict__ hsq) {
    __shared__ unsigned char smem[73728];
    unsigned char* AsB = smem;               // 3 bufs x [128 rows][128 B] = 48 KiB
    unsigned char* BsB = smem + 49152;       // 3 bufs x [64 rows][128 B]  = 24 KiB

    const int tid = threadIdx.x;
    const int lane = tid & 63;
    const int wave = tid >> 6;               // 0..7
    const int wm = wave & 3;                 // row block 0..3 (32 rows each)
    const int wn = wave >> 2;                // col block 0..1 (32 cols each)
    const int quad = lane >> 4;
    const int r = lane & 15;
    const int rx = r & 7;

    // bid = c(3b XCD) | q(6b): n-tile = q&7, m-tile = c*8 + (q>>3)
    const int bid = blockIdx.x;              // 0..511
    const int c_ = bid & 7, q_ = bid >> 3;
    const int n0 = (q_ & 7) * 64;
    const int m0 = ((c_ << 3) | (q_ >> 3)) * 128;

    f32x4 acc[2][2];
    #pragma unroll
    for (int i = 0; i < 2; ++i)
        #pragma unroll
        for (int j = 0; j < 2; ++j) acc[i][j] = (f32x4)(0.0f);

    const int lrow8 = lane >> 3;                      // 0..7 (row within 8-row group)
    const int gch8 = (lane & 7) ^ lrow8;              // pre-swizzled 16B source chunk

    const char* a0 = (const char*)xb + (size_t)(m0 + wave * 16 + lrow8) * (NX * 2) + gch8 * 16;
    const char* a1 = a0 + (size_t)8 * (NX * 2);
    const char* bsrc = (const char*)wfcb + (size_t)(n0 + wave * 8 + lrow8) * (NX * 2) + gch8 * 16;

    auto stage = [&](int bi, int k0) {                // 3 loads per wave, uniform
        glld16(a0 + (size_t)k0 * 2, AsB + bi * 16384 + (wave * 16) * 128);
        glld16(a1 + (size_t)k0 * 2, AsB + bi * 16384 + (wave * 16 + 8) * 128);
        glld16(bsrc + (size_t)k0 * 2, BsB + bi * 8192 + (wave * 8) * 128);
    };

    stage(0, 0);
    stage(1, 64);

    int cb = 0, sb = 2;
    #pragma unroll 1
    for (int it = 0; it < NX / 64; ++it) {            // 32 iters
        if (it == NX / 64 - 1) { asm volatile("s_waitcnt vmcnt(0)" ::: "memory"); }
        else                   { asm volatile("s_waitcnt vmcnt(3)" ::: "memory"); }
        __builtin_amdgcn_sched_barrier(0);
        __builtin_amdgcn_s_barrier();
        __builtin_amdgcn_sched_barrier(0);
        if (it + 2 < NX / 64) stage(sb, it * 64 + 128);
        __builtin_amdgcn_sched_barrier(0);
        const unsigned char* ab = AsB + cb * 16384;
        const unsigned char* bb = BsB + cb * 8192;
        #pragma unroll
        for (int s = 0; s < 2; ++s) {
            const int ch = ((s * 4 + quad) ^ rx) * 16;
            bf16x8 af[2], bfv[2];
            #pragma unroll
            for (int i = 0; i < 2; ++i)
                af[i] = *(const bf16x8*)(ab + (wm * 32 + i * 16 + r) * 128 + ch);
            #pragma unroll
            for (int j = 0; j < 2; ++j)
                bfv[j] = *(const bf16x8*)(bb + (wn * 32 + j * 16 + r) * 128 + ch);
            #pragma unroll
            for (int i = 0; i < 2; ++i)
                #pragma unroll
                for (int j = 0; j < 2; ++j)
                    acc[i][j] = __builtin_amdgcn_mfma_f32_16x16x32_bf16(af[i], bfv[j], acc[i][j], 0, 0, 0);
        }
        cb = (cb == 2) ? 0 : cb + 1;
        sb = (sb == 2) ? 0 : sb + 1;
    }

    // ---- epilogue: bias + relu -> hb, hsq partial (shuffle + atomic) ----
    float p[2][4];
    #pragma unroll
    for (int i = 0; i < 2; ++i)
        #pragma unroll
        for (int rr = 0; rr < 4; ++rr) p[i][rr] = 0.0f;

    #pragma unroll
    for (int j = 0; j < 2; ++j) {
        int col = n0 + wn * 32 + j * 16 + r;
        float bias = b_fc[col];
        #pragma unroll
        for (int i = 0; i < 2; ++i) {
            int rowb = m0 + wm * 32 + i * 16 + quad * 4;
            #pragma unroll
            for (int rr = 0; rr < 4; ++rr) {
                float v = fmaxf(acc[i][j][rr] + bias, 0.0f);
                hb[(size_t)(rowb + rr) * NH + col] = f2bf(v);
                p[i][rr] += v * v;
            }
        }
    }
    #pragma unroll
    for (int mask = 1; mask < 16; mask <<= 1)
        #pragma unroll
        for (int i = 0; i < 2; ++i)
            #pragma unroll
            for (int rr = 0; rr < 4; ++rr)
                p[i][rr] += __shfl_xor(p[i][rr], mask);
    if (r == 0) {
        #pragma unroll
        for (int i = 0; i < 2; ++i)
            #pragma unroll
            for (int rr = 0; rr < 4; ++rr)
                atomicAdd(&hsq[m0 + wm * 32 + i * 16 + quad * 4 + rr], p[i][rr]);
    }
}

// ---------------- GEMM2 fused with per-row LSE (single pass over out) ----------------
// NU=1  =>  t = -log1p(d)  =>  exp(t) = 1/(1+d): softmax denominator is a v_rcp.
// M=32 x N=1024 (in-block LSE), grid 256 = 1 block/CU.
// R7 made the K-loop barrier-free (B staging wave-private, A staged once).
// R8: exploit that freedom with 4x the TLP -- 1024 threads = 16 waves =
// 4 waves/SIMD, each running a private {issue 4 glld16; vmcnt(4); compute}
// pipeline. Wave w owns cols [w*64,+64): acc 2x4 (32 VGPR). LDS unchanged:
// A 32 KiB staged once (wave w stages k-slab w) + B 2x64 KiB. s_setprio(1)
// around the MFMA cluster (T5: pays when waves drift, which they now do).
__global__ __launch_bounds__(1024, 4) void gemm2_kernel(const unsigned short* __restrict__ hb,
                                                        const unsigned short* __restrict__ wqb,
                                                        const float* __restrict__ hsq,
                                                        const float* __restrict__ wqsq,
                                                        float* __restrict__ out) {
    __shared__ unsigned char smem[163840];
    char* As = (char*)smem;                  // [16 slabs][32 rows][64 B] = 32 KiB (staged once)
    char* Bs = (char*)smem + 32768;          // [buf][1024 rows][64 B] = 2 x 64 KiB

    const int tid = threadIdx.x;
    const int lane = tid & 63;
    const int wave = tid >> 6;               // 0..15 -> col slab [wave*64, +64)
    const int quad = lane >> 4;
    const int r = lane & 15;
    const int m0 = blockIdx.x * 32;          // 256 blocks

    f32x4 acc[2][4];
    #pragma unroll
    for (int i = 0; i < 2; ++i)
        #pragma unroll
        for (int j = 0; j < 4; ++j) acc[i][j] = (f32x4)(0.0f);

    const int lrow = lane >> 2;                       // 0..15
    const int gch = (lane & 3) ^ ((lrow >> 1) & 3);   // swizzled 16B chunk
    const int fsw = (quad ^ ((r >> 1) & 3)) * 16;

    const char* bsrc = (const char*)wqb + (size_t)(wave * 64 + lrow) * (NH * 2) + gch * 16;

    auto stageB = [&](int buf, int k0) {
        #pragma unroll
        for (int c = 0; c < 4; ++c)                   // this wave's 64 B-rows
            glld16(bsrc + (size_t)(c * 16 * NH + k0) * 2,
                   Bs + buf * 65536 + (wave * 64 + c * 16) * 64);
    };

    // ---- prologue: wave w stages A k-slab w (2 glld16) + its B(0) rows ----
    #pragma unroll
    for (int half = 0; half < 2; ++half)
        glld16((const char*)hb + (size_t)(m0 + half * 16 + lrow) * (NH * 2) + wave * 64 + gch * 16,
               As + wave * 2048 + half * 1024);
    stageB(0, 0);
    asm volatile("s_waitcnt vmcnt(4)" ::: "memory");  // A landed; B(0) may fly
    __builtin_amdgcn_sched_barrier(0);
    __builtin_amdgcn_s_barrier();
    __builtin_amdgcn_sched_barrier(0);

    #pragma unroll 1
    for (int it = 0; it < NH / 32; ++it) {            // 16 iters, NO barriers
        if (it + 1 < NH / 32) stageB((it + 1) & 1, it * 32 + 32);
        __builtin_amdgcn_sched_barrier(0);
        if (it == NH / 32 - 1) { asm volatile("s_waitcnt vmcnt(0)" ::: "memory"); }
        else                   { asm volatile("s_waitcnt vmcnt(4)" ::: "memory"); }
        __builtin_amdgcn_sched_barrier(0);
        const char* ab = As + it * 2048;
        const char* bb = Bs + (it & 1) * 65536;
        bf16x8 af[2], bfv[4];
        #pragma unroll
        for (int i = 0; i < 2; ++i)
            af[i] = *(const bf16x8*)(ab + (i * 16 + r) * 64 + fsw);
        #pragma unroll
        for (int j = 0; j < 4; ++j)
            bfv[j] = *(const bf16x8*)(bb + (wave * 64 + j * 16 + r) * 64 + fsw);
        __builtin_amdgcn_s_setprio(1);
        #pragma unroll
        for (int i = 0; i < 2; ++i)
            #pragma unroll
            for (int j = 0; j < 4; ++j)
                acc[i][j] = __builtin_amdgcn_mfma_f32_16x16x32_bf16(af[i], bfv[j], acc[i][j], 0, 0, 0);
        __builtin_amdgcn_s_setprio(0);
    }

    // ---- epilogue: d, t, row-sums of exp(t) = 1/(1+d), LSE, store ----
    float hs_[2][4];
    #pragma unroll
    for (int i = 0; i < 2; ++i)
        #pragma unroll
        for (int rr = 0; rr < 4; ++rr)
            hs_[i][rr] = hsq[m0 + i * 16 + quad * 4 + rr];

    float srow[2][4];
    #pragma unroll
    for (int i = 0; i < 2; ++i)
        #pragma unroll
        for (int rr = 0; rr < 4; ++rr) srow[i][rr] = 0.0f;

    #pragma unroll
    for (int j = 0; j < 4; ++j) {
        float wqv = wqsq[wave * 64 + j * 16 + r];
        #pragma unroll
        for (int i = 0; i < 2; ++i) {
            #pragma unroll
            for (int rr = 0; rr < 4; ++rr) {
                float d = hs_[i][rr] - 2.0f * acc[i][j][rr] + wqv;
                d = fmaxf(d, 0.0f);
                float onepd = 1.0f + d;
                srow[i][rr] += __builtin_amdgcn_rcpf(onepd);
                acc[i][j][rr] = -__logf(onepd);       // keep t in-register
            }
        }
    }
    #pragma unroll
    for (int mask = 1; mask < 16; mask <<= 1)
        #pragma unroll
        for (int i = 0; i < 2; ++i)
            #pragma unroll
            for (int rr = 0; rr < 4; ++rr)
                srow[i][rr] += __shfl_xor(srow[i][rr], mask);

    float* smemF = (float*)smem;                      // reuse As region
    __syncthreads();                                  // ALL waves out of K-loop first
    if (r == 0) {
        #pragma unroll
        for (int i = 0; i < 2; ++i)
            #pragma unroll
            for (int rr = 0; rr < 4; ++rr)
                smemF[wave * 32 + i * 16 + quad * 4 + rr] = srow[i][rr];
    }
    __syncthreads();
    if (tid < 32) {
        float S = 0.0f;
        #pragma unroll
        for (int w = 0; w < 16; ++w) S += smemF[w * 32 + tid];
        smemF[512 + tid] = __logf(S);
    }
    __syncthreads();

    #pragma unroll
    for (int i = 0; i < 2; ++i) {
        #pragma unroll
        for (int rr = 0; rr < 4; ++rr) {
            float l = smemF[512 + i * 16 + quad * 4 + rr];
            size_t rowoff = (size_t)(m0 + i * 16 + quad * 4 + rr) * NY + wave * 64 + r;
            #pragma unroll
            for (int j = 0; j < 4; ++j)
                out[rowoff + j * 16] = acc[i][j][rr] - l;
        }
    }
}

extern "C" void kernel_launch(void* const* d_in, const int* in_sizes, int n_in,
                              void* d_out, int out_size, void* d_ws, size_t ws_size,
                              hipStream_t stream) {
    const float* x    = (const float*)d_in[0];
    const float* W_fc = (const float*)d_in[1];
    const float* b_fc = (const float*)d_in[2];
    const float* W_q  = (const float*)d_in[3];
    float* out = (float*)d_out;

    char* ws = (char*)d_ws;
    unsigned short* xb   = (unsigned short*)(ws);                        // 32 MiB
    unsigned short* wfcb = (unsigned short*)(ws + 33554432);             // 2 MiB
    unsigned short* wqb  = (unsigned short*)(ws + 35651584);             // 1 MiB
    float*          wqsq = (float*)(ws + 36700160);                      // 4 KiB
    unsigned short* hb   = (unsigned short*)(ws + 36704256);             // 8 MiB
    float*          hsq  = (float*)(ws + 45092864);                      // 32 KiB

    prep_kernel<<<EW_BLOCKS + WQ_BLOCKS, 256, 0, stream>>>(x, W_fc, W_q, xb, wfcb, wqb, wqsq, hsq);
    gemm1_kernel<<<512, 512, 0, stream>>>(xb, wfcb, b_fc, hb, hsq);
    gemm2_kernel<<<B_ROWS / 32, 1024, 0, stream>>>(hb, wqb, hsq, wqsq, out);
}